// Round 13
// baseline (752.745 us; speedup 1.0000x reference)
//
#include <hip/hip_runtime.h>
#include <stdint.h>

#define NN 50000
#define NE 600000
#define NR 16
#define NG 128
#define TS 128
#define SCAN_B 512
#define NB_SCAN ((NN + SCAN_B - 1) / SCAN_B)   // 98
#define MAXB 1024

typedef short bf16x8 __attribute__((ext_vector_type(8)));
typedef float f32x4 __attribute__((ext_vector_type(4)));

static __device__ __forceinline__ unsigned short f2bf(float x) {
    unsigned int b = __float_as_uint(x);
    b += 0x7FFFu + ((b >> 16) & 1u);
    return (unsigned short)(b >> 16);
}
static __device__ __forceinline__ float bf2f(unsigned short u) {
    return __uint_as_float(((unsigned int)u) << 16);
}

// ---------------- histograms / sort ----------------
// bucket key = dchunk*SB + (src/nps)*NR + rel   (SB = S*NR; rel in low bits)

__global__ void k_hist(const int* __restrict__ rel, const int* __restrict__ dst,
                       const int* __restrict__ src,
                       int* __restrict__ bcnt, int* __restrict__ ncnt,
                       int npc, int nps, int SB, int B) {
    __shared__ int lh[MAXB];
    for (int i = threadIdx.x; i < B; i += 256) lh[i] = 0;
    __syncthreads();
    for (int e = blockIdx.x * blockDim.x + threadIdx.x; e < NE; e += gridDim.x * blockDim.x) {
        int d = dst[e];
        int key = (d / npc) * SB + (src[e] / nps) * NR + rel[e];
        atomicAdd(&lh[key], 1);
        atomicAdd(&ncnt[d], 1);
    }
    __syncthreads();
    for (int i = threadIdx.x; i < B; i += 256) atomicAdd(&bcnt[i], lh[i]);
}

// 3-phase parallel node-count scan -> rowptr[NN+1]
__global__ void k_scan1(const int* __restrict__ ncnt, int* __restrict__ bsum) {
    __shared__ int s[SCAN_B];
    int i = blockIdx.x * SCAN_B + threadIdx.x;
    s[threadIdx.x] = (i < NN) ? ncnt[i] : 0;
    __syncthreads();
    for (int off = SCAN_B / 2; off > 0; off >>= 1) {
        if (threadIdx.x < off) s[threadIdx.x] += s[threadIdx.x + off];
        __syncthreads();
    }
    if (threadIdx.x == 0) bsum[blockIdx.x] = s[0];
}

__global__ void k_scan2(const int* __restrict__ bsum, int* __restrict__ bpref, int* __restrict__ rowptr) {
    if (threadIdx.x == 0 && blockIdx.x == 0) {
        int run = 0;
        for (int b = 0; b < NB_SCAN; ++b) { bpref[b] = run; run += bsum[b]; }
        rowptr[NN] = run;
    }
}

__global__ void k_scan3(const int* __restrict__ ncnt, const int* __restrict__ bpref,
                        int* __restrict__ rowptr) {
    __shared__ int s[SCAN_B];
    int i = blockIdx.x * SCAN_B + threadIdx.x;
    int val = (i < NN) ? ncnt[i] : 0;
    s[threadIdx.x] = val;
    __syncthreads();
    for (int off = 1; off < SCAN_B; off <<= 1) {
        int x = (threadIdx.x >= off) ? s[threadIdx.x - off] : 0;
        __syncthreads();
        s[threadIdx.x] += x;
        __syncthreads();
    }
    if (i < NN) rowptr[i] = bpref[blockIdx.x] + s[threadIdx.x] - val;
}

// bucket scan + parallel tile map build
__global__ __launch_bounds__(1024)
void k_scan_buckets(const int* __restrict__ bcnt, int B, int npc, int SB,
                    const int* __restrict__ rowptr,
                    int* __restrict__ boff, int* __restrict__ tstart,
                    int4* __restrict__ tilemap) {
    __shared__ int s1[MAXB], s2[MAXB];
    __shared__ int e_ex[MAXB + 1], t_ex[MAXB + 1];
    int tid = threadIdx.x;
    int v1 = (tid < B) ? bcnt[tid] : 0;
    int v2 = (v1 + TS - 1) / TS;
    s1[tid] = v1; s2[tid] = v2;
    __syncthreads();
    for (int off = 1; off < MAXB; off <<= 1) {
        int a1 = (tid >= off) ? s1[tid - off] : 0;
        int a2 = (tid >= off) ? s2[tid - off] : 0;
        __syncthreads();
        s1[tid] += a1; s2[tid] += a2;
        __syncthreads();
    }
    if (tid < B) {
        e_ex[tid] = s1[tid] - v1;
        t_ex[tid] = s2[tid] - v2;
        boff[tid] = e_ex[tid];
        tstart[tid] = t_ex[tid];
        if (tid == B - 1) {
            e_ex[B] = s1[tid]; t_ex[B] = s2[tid];
            boff[B] = s1[tid]; tstart[B] = s2[tid];
        }
    }
    __syncthreads();
    int T = t_ex[B];
    for (int t = tid; t < T; t += 1024) {
        int lo = 0, hi = B - 1;
        while (lo < hi) {
            int mid = (lo + hi + 1) >> 1;
            if (t_ex[mid] <= t) lo = mid; else hi = mid - 1;
        }
        int b = lo;
        int tt = t - t_ex[b];
        int v1b = e_ex[b + 1] - e_ex[b];
        int rem = v1b - tt * TS;
        int cnt = rem < TS ? rem : TS;
        int chunk = b / SB;
        int nstart = chunk * npc; if (nstart > NN) nstart = NN;
        tilemap[t] = make_int4(b & (NR - 1), e_ex[b] + tt * TS, cnt, rowptr[nstart]);
    }
}

// scatter: store SOURCE NODE id at bucket-sorted slot
__global__ void k_scatter(const int* __restrict__ rel, const int* __restrict__ dst,
                          const int* __restrict__ src,
                          const int* __restrict__ boff, int* __restrict__ cursor,
                          const int* __restrict__ rowptr, int* __restrict__ ncur,
                          int* __restrict__ srcs, int* __restrict__ dpos,
                          int npc, int nps, int SB, int B) {
    __shared__ int lh[MAXB];
    const int CH = 4096;
    int e0 = blockIdx.x * CH;
    for (int i = threadIdx.x; i < B; i += 256) lh[i] = 0;
    __syncthreads();
    for (int i = threadIdx.x; i < CH; i += 256) {
        int e = e0 + i;
        if (e < NE) atomicAdd(&lh[(dst[e] / npc) * SB + (src[e] / nps) * NR + rel[e]], 1);
    }
    __syncthreads();
    for (int i = threadIdx.x; i < B; i += 256) {
        int c = lh[i];
        lh[i] = (c > 0) ? atomicAdd(&cursor[i], c) : 0;
    }
    __syncthreads();
    for (int i = threadIdx.x; i < CH; i += 256) {
        int e = e0 + i;
        if (e < NE) {
            int d = dst[e];
            int s = src[e];
            int b = (d / npc) * SB + (s / nps) * NR + rel[e];
            int p = boff[b] + atomicAdd(&lh[b], 1);
            int pd = rowptr[d] + atomicAdd(&ncur[d], 1);
            srcs[p] = s;
            dpos[p] = pd;
        }
    }
}

// ---------------- conversions ----------------

__global__ void k_hconv(const float* __restrict__ h, unsigned short* __restrict__ hb, int n4) {
    int i = blockIdx.x * 256 + threadIdx.x;
    if (i < n4) {
        float4 v = reinterpret_cast<const float4*>(h)[i];
        ushort4 o = { f2bf(v.x), f2bf(v.y), f2bf(v.z), f2bf(v.w) };
        reinterpret_cast<ushort4*>(hb)[i] = o;
    }
}

__global__ void k_wconv_all(const float* Wr0, const float* Wr1, const float* Wr2,
                            const float* Wl0, const float* Wl1, const float* Wl2,
                            unsigned short* Wt0, unsigned short* Wt1, unsigned short* Wt2,
                            unsigned short* Wlt0, unsigned short* Wlt1, unsigned short* Wlt2) {
    const float* W; unsigned short* O; int R, Kd, Nd;
    switch (blockIdx.y) {
        case 0:  W = Wr0; O = Wt0;  R = NR; Kd = 128; Nd = 128; break;
        case 1:  W = Wr1; O = Wt1;  R = NR; Kd = 128; Nd = 256; break;
        case 2:  W = Wr2; O = Wt2;  R = NR; Kd = 256; Nd = 128; break;
        case 3:  W = Wl0; O = Wlt0; R = 1;  Kd = 128; Nd = 128; break;
        case 4:  W = Wl1; O = Wlt1; R = 1;  Kd = 128; Nd = 256; break;
        default: W = Wl2; O = Wlt2; R = 1;  Kd = 256; Nd = 128; break;
    }
    int total = R * Kd * Nd;
    for (int i = blockIdx.x * 256 + threadIdx.x; i < total; i += gridDim.x * 256) {
        int r = i / (Kd * Nd);
        int rem = i - r * Kd * Nd;
        int k = rem / Nd;
        int n = rem - k * Nd;
        O[((size_t)r * Nd + n) * Kd + k] = f2bf(W[i]);
    }
}

// ---------------- MFMA dense GEMM (LDS-staged, proven) ----------------

template<int K>
__global__ __launch_bounds__(256, 4)
void k_dense_mfma(const unsigned short* __restrict__ hb,
                  const unsigned short* __restrict__ Wlt,   // [ldn][K] bf16
                  const float* __restrict__ bias,
                  float* __restrict__ outbuf, int ldn) {
    __shared__ __align__(16) unsigned short As[128][72];
    __shared__ __align__(16) unsigned short Bs[128][72];
    const int tid = threadIdx.x;
    const int row0 = blockIdx.x * 128;
    const int colbase = blockIdx.y * 128;
    const int lane = tid & 63, w = tid >> 6;
    const int quad = lane >> 4, col = lane & 15;
    const int srow = tid >> 3, sk = (tid & 7) * 8;

    f32x4 acc[8][2];
#pragma unroll
    for (int i = 0; i < 8; ++i) { acc[i][0] = 0.f; acc[i][1] = 0.f; }

    for (int k0 = 0; k0 < K; k0 += 64) {
        __syncthreads();
#pragma unroll
        for (int pp = 0; pp < 4; ++pp) {
            int rw = pp * 32 + srow;
            int ar = row0 + rw; if (ar >= NN) ar = NN - 1;
            *reinterpret_cast<uint4*>(&As[rw][sk]) =
                *reinterpret_cast<const uint4*>(hb + (size_t)ar * K + k0 + sk);
            *reinterpret_cast<uint4*>(&Bs[rw][sk]) =
                *reinterpret_cast<const uint4*>(Wlt + (size_t)(colbase + rw) * K + k0 + sk);
        }
        __syncthreads();
#pragma unroll
        for (int s = 0; s < 2; ++s) {
            bf16x8 bf0 = *reinterpret_cast<const bf16x8*>(&Bs[w * 32 + col][s * 32 + quad * 8]);
            bf16x8 bf1 = *reinterpret_cast<const bf16x8*>(&Bs[w * 32 + 16 + col][s * 32 + quad * 8]);
#pragma unroll
            for (int rt = 0; rt < 8; ++rt) {
                bf16x8 af = *reinterpret_cast<const bf16x8*>(&As[rt * 16 + col][s * 32 + quad * 8]);
                acc[rt][0] = __builtin_amdgcn_mfma_f32_16x16x32_bf16(af, bf0, acc[rt][0], 0, 0, 0);
                acc[rt][1] = __builtin_amdgcn_mfma_f32_16x16x32_bf16(af, bf1, acc[rt][1], 0, 0, 0);
            }
        }
    }
    float bv0 = bias[colbase + w * 32 + col];
    float bv1 = bias[colbase + w * 32 + 16 + col];
#pragma unroll
    for (int rt = 0; rt < 8; ++rt) {
#pragma unroll
        for (int reg = 0; reg < 4; ++reg) {
            int r = row0 + rt * 16 + quad * 4 + reg;
            if (r < NN) {
                float* dp = outbuf + (size_t)r * ldn + colbase + w * 32;
                dp[col] = acc[rt][0][reg] + bv0;
                dp[16 + col] = acc[rt][1][reg] + bv1;
            }
        }
    }
}

// ---------------- MFMA edge GEMM (round-8 shape, pad 136, XCD-swizzled tiles):
// 1 tile/block, full 128-K A slice in LDS, B direct from global ----------------

template<int K>
__global__ __launch_bounds__(256, 4)
void k_edge_mfma(const unsigned short* __restrict__ hb,
                 const unsigned short* __restrict__ Wt,   // [NR][ldn][K] bf16
                 int ldn, int colbase,
                 const int* __restrict__ srcs, const int* __restrict__ dpos,
                 const int4* __restrict__ tilemap, const int* __restrict__ tstart,
                 int chunkBase, int SB,
                 unsigned short* __restrict__ msg, int capRows) {
    const int tb0 = tstart[chunkBase];
    const int T = tstart[chunkBase + SB] - tb0;
    // XCD-aware swizzle: round-robin dispatch puts blockIdx.x&7 on XCD x;
    // give each XCD a CONTIGUOUS tile range so its private L2 holds one src window.
    const int per = (T + 7) >> 3;
    const int tt = (blockIdx.x & 7) * per + (blockIdx.x >> 3);
    if (tt >= T) return;
    const int4 tm = tilemap[tb0 + tt];
    const int r = tm.x, e0 = tm.y, cnt = tm.z, cES = tm.w;

    __shared__ __align__(16) unsigned short As[128][136];
    __shared__ int s_src[TS], s_out[TS];
    const int tid = threadIdx.x;
    if (tid < TS) {
        int ei = e0 + (tid < cnt ? tid : cnt - 1);
        s_src[tid] = srcs[ei];
        int row = dpos[ei] - cES;
        s_out[tid] = (tid < cnt && row < capRows) ? row : -1;
    }
    __syncthreads();

    const unsigned short* Wb = Wt + ((size_t)r * ldn + colbase) * K;
    const int lane = tid & 63, w = tid >> 6;
    const int quad = lane >> 4, col = lane & 15;
    const int asr = tid >> 4, ask = (tid & 15) * 8;

    f32x4 acc[8][2];
#pragma unroll
    for (int i = 0; i < 8; ++i) { acc[i][0] = 0.f; acc[i][1] = 0.f; }

    for (int kk = 0; kk < K; kk += 128) {
        if (kk) __syncthreads();
#pragma unroll
        for (int q = 0; q < 8; ++q) {
            int rw = q * 16 + asr;
            *reinterpret_cast<uint4*>(&As[rw][ask]) =
                *reinterpret_cast<const uint4*>(hb + (size_t)s_src[rw] * K + kk + ask);
        }
        __syncthreads();
#pragma unroll
        for (int k32 = 0; k32 < 4; ++k32) {
            bf16x8 bf0 = *reinterpret_cast<const bf16x8*>(
                Wb + (size_t)(w * 32 + col) * K + kk + k32 * 32 + quad * 8);
            bf16x8 bf1 = *reinterpret_cast<const bf16x8*>(
                Wb + (size_t)(w * 32 + 16 + col) * K + kk + k32 * 32 + quad * 8);
#pragma unroll
            for (int rt = 0; rt < 8; ++rt) {
                bf16x8 af = *reinterpret_cast<const bf16x8*>(&As[rt * 16 + col][k32 * 32 + quad * 8]);
                acc[rt][0] = __builtin_amdgcn_mfma_f32_16x16x32_bf16(af, bf0, acc[rt][0], 0, 0, 0);
                acc[rt][1] = __builtin_amdgcn_mfma_f32_16x16x32_bf16(af, bf1, acc[rt][1], 0, 0, 0);
            }
        }
    }
#pragma unroll
    for (int rt = 0; rt < 8; ++rt) {
#pragma unroll
        for (int reg = 0; reg < 4; ++reg) {
            int m = rt * 16 + quad * 4 + reg;
            int o = s_out[m];
            if (o >= 0) {
                unsigned short* dp = msg + (size_t)o * 128 + w * 32;
                dp[col] = f2bf(acc[rt][0][reg]);
                dp[16 + col] = f2bf(acc[rt][1][reg]);
            }
        }
    }
}

// segmented reduce: one wave per node, 4-way unrolled row loads (round-10 proven)
__global__ __launch_bounds__(256)
void k_reduce(const unsigned short* __restrict__ msg,
              const float* __restrict__ selfb, int ld_self, int co_self,
              unsigned short* __restrict__ out_bf, int ld_bf, int co_bf,
              float* __restrict__ out_f32, int ld_f32, int co_f32,
              const int* __restrict__ rowptr, int n0, int npc, int capRows) {
    int idx = blockIdx.x * 4 + (threadIdx.x >> 6);
    int n = n0 + idx;
    if (idx >= npc || n >= NN) return;
    int lane = threadIdx.x & 63;
    int cES = rowptr[n0];
    float2 acc = *reinterpret_cast<const float2*>(selfb + (size_t)n * ld_self + co_self + lane * 2);
    int j0 = rowptr[n], j1 = rowptr[n + 1];
    int jcap = cES + capRows; if (j1 > jcap) j1 = jcap;
    const unsigned int* mp = reinterpret_cast<const unsigned int*>(msg) + lane;
    int j = j0;
    for (; j + 4 <= j1; j += 4) {
        unsigned int m0 = mp[(size_t)(j + 0 - cES) * 64];
        unsigned int m1 = mp[(size_t)(j + 1 - cES) * 64];
        unsigned int m2 = mp[(size_t)(j + 2 - cES) * 64];
        unsigned int m3 = mp[(size_t)(j + 3 - cES) * 64];
        acc.x += bf2f((unsigned short)(m0 & 0xffffu)) + bf2f((unsigned short)(m1 & 0xffffu))
               + bf2f((unsigned short)(m2 & 0xffffu)) + bf2f((unsigned short)(m3 & 0xffffu));
        acc.y += bf2f((unsigned short)(m0 >> 16)) + bf2f((unsigned short)(m1 >> 16))
               + bf2f((unsigned short)(m2 >> 16)) + bf2f((unsigned short)(m3 >> 16));
    }
    for (; j < j1; ++j) {
        unsigned int m = mp[(size_t)(j - cES) * 64];
        acc.x += bf2f((unsigned short)(m & 0xffffu));
        acc.y += bf2f((unsigned short)(m >> 16));
    }
    acc.x = acc.x > 0.f ? acc.x : 0.f;
    acc.y = acc.y > 0.f ? acc.y : 0.f;
    if (out_bf) {
        unsigned int o = (unsigned int)f2bf(acc.x) | ((unsigned int)f2bf(acc.y) << 16);
        *reinterpret_cast<unsigned int*>(out_bf + (size_t)n * ld_bf + co_bf + lane * 2) = o;
    }
    if (out_f32) {
        *reinterpret_cast<float2*>(out_f32 + (size_t)n * ld_f32 + co_f32 + lane * 2) = acc;
    }
}

// ---------------- pooling / fused MLP head ----------------

__global__ void k_pool(const float* __restrict__ h, const int* __restrict__ gid,
                       float* __restrict__ hg, float* __restrict__ gcnt) {
    const int c = threadIdx.x;  // 128
    int n0 = blockIdx.x * 64;
    if (n0 >= NN) return;
    int end = n0 + 64; if (end > NN) end = NN;
    int cur = gid[n0];
    float run = 0.f, crun = 0.f;
    for (int n = n0; n < end; ++n) {
        int g = gid[n];
        if (g != cur) {
            atomicAdd(&hg[cur * 128 + c], run);
            if (c == 0) atomicAdd(&gcnt[cur], crun);
            run = 0.f; crun = 0.f; cur = g;
        }
        run += h[(size_t)n * 128 + c];
        crun += 1.f;
    }
    atomicAdd(&hg[cur * 128 + c], run);
    if (c == 0) atomicAdd(&gcnt[cur], crun);
}

__global__ __launch_bounds__(256)
void k_head(const float* __restrict__ hg, const float* __restrict__ gcnt,
            const float* __restrict__ Wh0, const float* __restrict__ bh0,
            const float* __restrict__ Wh1, const float* __restrict__ bh1,
            const float* __restrict__ Wh2, const float* __restrict__ bh2,
            const float* __restrict__ Wc, const float* __restrict__ bc,
            float* __restrict__ out) {
    __shared__ float x0[128], x1[128], x2[256], x3[128], sl[8];
    int g = blockIdx.x, t = threadIdx.x;
    if (t < 128) {
        float c = gcnt[g];
        x0[t] = hg[g * 128 + t] / (c > 1.f ? c : 1.f);
    }
    __syncthreads();
    if (t < 128) {
        float a = bh0[t];
        for (int k = 0; k < 128; ++k) a += x0[k] * Wh0[k * 128 + t];
        x1[t] = a > 0.f ? a : 0.f;
    }
    __syncthreads();
    {
        float a = bh1[t];
        for (int k = 0; k < 128; ++k) a += x1[k] * Wh1[k * 256 + t];
        x2[t] = a > 0.f ? a : 0.f;
    }
    __syncthreads();
    if (t < 128) {
        float a = bh2[t];
        for (int k = 0; k < 256; ++k) a += x2[k] * Wh2[k * 128 + t];
        x3[t] = a > 0.f ? a : 0.f;
    }
    __syncthreads();
    if (t < 8) {
        float a = bc[t];
        for (int k = 0; k < 128; ++k) a += x3[k] * Wc[k * 8 + t];
        sl[t] = a;
    }
    __syncthreads();
    if (t == 0) {
        float m = sl[0];
        for (int c = 1; c < 8; ++c) m = sl[c] > m ? sl[c] : m;
        float s = 0.f, e[8];
        for (int c = 0; c < 8; ++c) { e[c] = expf(sl[c] - m); s += e[c]; }
        for (int c = 0; c < 8; ++c) out[g * 8 + c] = e[c] / s;
    }
}

// ---------------- launcher ----------------

extern "C" void kernel_launch(void* const* d_in, const int* in_sizes, int n_in,
                              void* d_out, int out_size, void* d_ws, size_t ws_size,
                              hipStream_t stream) {
    const float* h0   = (const float*)d_in[0];
    const int* src    = (const int*)d_in[1];
    const int* dst    = (const int*)d_in[2];
    const int* rel    = (const int*)d_in[3];
    const int* gid    = (const int*)d_in[4];
    const float* Wr0  = (const float*)d_in[5];
    const float* Wl0  = (const float*)d_in[6];
    const float* b0   = (const float*)d_in[7];
    const float* Wr1  = (const float*)d_in[8];
    const float* Wl1  = (const float*)d_in[9];
    const float* b1   = (const float*)d_in[10];
    const float* Wr2  = (const float*)d_in[11];
    const float* Wl2  = (const float*)d_in[12];
    const float* b2   = (const float*)d_in[13];
    const float* Wh0  = (const float*)d_in[14];
    const float* bh0  = (const float*)d_in[15];
    const float* Wh1  = (const float*)d_in[16];
    const float* bh1  = (const float*)d_in[17];
    const float* Wh2  = (const float*)d_in[18];
    const float* bh2  = (const float*)d_in[19];
    const float* Wc   = (const float*)d_in[20];
    const float* bc   = (const float*)d_in[21];
    float* out = (float*)d_out;

    // workspace layout (256B-aligned blocks); zero-init arrays contiguous
    char* p = (char*)d_ws;
    auto alloc = [&](size_t bytes) { char* q = p; p += (bytes + 255) & ~(size_t)255; return q; };
    float* bufS  = (float*)alloc((size_t)NN * 256 * 4);
    unsigned short* hbA = (unsigned short*)alloc((size_t)NN * 256 * 2);
    unsigned short* hbB = (unsigned short*)alloc((size_t)NN * 128 * 2);
    unsigned short* Wt0 = (unsigned short*)alloc((size_t)NR * 128 * 128 * 2);
    unsigned short* Wt1 = (unsigned short*)alloc((size_t)NR * 256 * 128 * 2);
    unsigned short* Wt2 = (unsigned short*)alloc((size_t)NR * 128 * 256 * 2);
    unsigned short* Wlt0 = (unsigned short*)alloc((size_t)128 * 128 * 2);
    unsigned short* Wlt1 = (unsigned short*)alloc((size_t)256 * 128 * 2);
    unsigned short* Wlt2 = (unsigned short*)alloc((size_t)128 * 256 * 2);
    int* srcs    = (int*)alloc((size_t)NE * 4);
    int* dpos    = (int*)alloc((size_t)NE * 4);
    int* rowptr  = (int*)alloc((size_t)(NN + 1) * 4);
    int* bsum    = (int*)alloc(NB_SCAN * 4);
    int* bpref   = (int*)alloc(NB_SCAN * 4);
    int* boff    = (int*)alloc((MAXB + 1) * 4);
    int* tstart  = (int*)alloc((MAXB + 1) * 4);
    int4* tilemap = (int4*)alloc((size_t)(NE / TS + MAXB + 64) * 16);
    // ---- zero-init region (one memset) ----
    char* zbase  = p;
    int* bcnt    = (int*)alloc(MAXB * 4);
    int* cursor  = (int*)alloc(MAXB * 4);
    int* ncnt    = (int*)alloc((size_t)NN * 4);
    int* ncur    = (int*)alloc((size_t)NN * 4);
    float* hg    = (float*)alloc((size_t)NG * 128 * 4);
    float* gcnt  = (float*)alloc(NG * 4);
    size_t zlen  = (size_t)(p - zbase);
    unsigned short* msg = (unsigned short*)p;

    long long avail = (long long)ws_size - (long long)(p - (char*)d_ws);
    if (avail < (1 << 20)) avail = (1 << 20);
    long long capR64 = avail / 256;                 // bf16 rows of 128
    int C = 64;
    for (int c = 1; c <= 64; ++c) {
        double need = (double)NE / c * 1.15 + 4096.0;
        if ((double)capR64 >= need) { C = c; break; }
    }
    int npc = (NN + C - 1) / C;
    int S = MAXB / (C * NR); if (S < 1) S = 1;
    int SB = S * NR;
    int B = C * SB;
    int nps = (NN + S - 1) / S;
    int capRows = capR64 > 2000000000LL ? 2000000000 : (int)capR64;
    int TPC = (int)((double)NE / C * 1.15 / TS) + SB + 16;
    int RDB = (npc + 3) / 4;

    // preprocessing
    hipMemsetAsync(zbase, 0, zlen, stream);
    k_hist<<<256, 256, 0, stream>>>(rel, dst, src, bcnt, ncnt, npc, nps, SB, B);
    k_scan1<<<NB_SCAN, SCAN_B, 0, stream>>>(ncnt, bsum);
    k_scan2<<<1, 64, 0, stream>>>(bsum, bpref, rowptr);
    k_scan3<<<NB_SCAN, SCAN_B, 0, stream>>>(ncnt, bpref, rowptr);
    k_scan_buckets<<<1, MAXB, 0, stream>>>(bcnt, B, npc, SB, rowptr, boff, tstart, tilemap);
    k_scatter<<<(NE + 4095) / 4096, 256, 0, stream>>>(rel, dst, src, boff, cursor, rowptr, ncur, srcs, dpos, npc, nps, SB, B);

    k_hconv<<<(NN * 128 / 4 + 255) / 256, 256, 0, stream>>>(h0, hbA, NN * 128 / 4);
    k_wconv_all<<<dim3(512, 6), 256, 0, stream>>>(Wr0, Wr1, Wr2, Wl0, Wl1, Wl2,
                                                  Wt0, Wt1, Wt2, Wlt0, Wlt1, Wlt2);

    const int RB = (NN + TS - 1) / TS;  // 391

    // ---- layer 0: 128 -> 128 (in hbA[ld128], out hbB bf16[ld128]) ----
    k_dense_mfma<128><<<dim3(RB, 1), 256, 0, stream>>>(hbA, Wlt0, b0, bufS, 128);
    for (int c = 0; c < C; ++c) {
        k_edge_mfma<128><<<TPC, 256, 0, stream>>>(hbA, Wt0, 128, 0, srcs, dpos, tilemap, tstart, c * SB, SB, msg, capRows);
        k_reduce<<<RDB, 256, 0, stream>>>(msg, bufS, 128, 0, hbB, 128, 0, (float*)nullptr, 0, 0, rowptr, c * npc, npc, capRows);
    }

    // ---- layer 1: 128 -> 256 (in hbB[ld128], out hbA bf16[ld256]) ----
    k_dense_mfma<128><<<dim3(RB, 2), 256, 0, stream>>>(hbB, Wlt1, b1, bufS, 256);
    for (int half = 0; half < 2; ++half) {
        for (int c = 0; c < C; ++c) {
            k_edge_mfma<128><<<TPC, 256, 0, stream>>>(hbB, Wt1, 256, half * 128, srcs, dpos, tilemap, tstart, c * SB, SB, msg, capRows);
            k_reduce<<<RDB, 256, 0, stream>>>(msg, bufS, 256, half * 128, hbA, 256, half * 128, (float*)nullptr, 0, 0, rowptr, c * npc, npc, capRows);
        }
    }

    // ---- layer 2: 256 -> 128 (in hbA[ld256], out bufS fp32[ld128] in place) ----
    k_dense_mfma<256><<<dim3(RB, 1), 256, 0, stream>>>(hbA, Wlt2, b2, bufS, 128);
    for (int c = 0; c < C; ++c) {
        k_edge_mfma<256><<<TPC, 256, 0, stream>>>(hbA, Wt2, 128, 0, srcs, dpos, tilemap, tstart, c * SB, SB, msg, capRows);
        k_reduce<<<RDB, 256, 0, stream>>>(msg, bufS, 128, 0, (unsigned short*)nullptr, 0, 0, bufS, 128, 0, rowptr, c * npc, npc, capRows);
    }

    // mean pooling + fused MLP head
    k_pool<<<(NN + 63) / 64, 128, 0, stream>>>(bufS, gid, hg, gcnt);
    k_head<<<NG, 256, 0, stream>>>(hg, gcnt, Wh0, bh0, Wh1, bh1, Wh2, bh2, Wc, bc, out);
}

// Round 14
// 751.841 us; speedup vs baseline: 1.0012x; 1.0012x over previous
//
#include <hip/hip_runtime.h>
#include <stdint.h>

#define NN 50000
#define NE 600000
#define NR 16
#define NG 128
#define TS 128
#define SCAN_B 512
#define NB_SCAN ((NN + SCAN_B - 1) / SCAN_B)   // 98
#define MAXB 1024

typedef short bf16x8 __attribute__((ext_vector_type(8)));
typedef float f32x4 __attribute__((ext_vector_type(4)));

static __device__ __forceinline__ unsigned short f2bf(float x) {
    unsigned int b = __float_as_uint(x);
    b += 0x7FFFu + ((b >> 16) & 1u);
    return (unsigned short)(b >> 16);
}
static __device__ __forceinline__ float bf2f(unsigned short u) {
    return __uint_as_float(((unsigned int)u) << 16);
}

// ---------------- histograms / sort ----------------
// bucket key = dchunk*SB + (src/nps)*NR + rel   (SB = S*NR; rel in low bits)

__global__ void k_hist(const int* __restrict__ rel, const int* __restrict__ dst,
                       const int* __restrict__ src,
                       int* __restrict__ bcnt, int* __restrict__ ncnt,
                       int npc, int nps, int SB, int B) {
    __shared__ int lh[MAXB];
    for (int i = threadIdx.x; i < B; i += 256) lh[i] = 0;
    __syncthreads();
    for (int e = blockIdx.x * blockDim.x + threadIdx.x; e < NE; e += gridDim.x * blockDim.x) {
        int d = dst[e];
        int key = (d / npc) * SB + (src[e] / nps) * NR + rel[e];
        atomicAdd(&lh[key], 1);
        atomicAdd(&ncnt[d], 1);
    }
    __syncthreads();
    for (int i = threadIdx.x; i < B; i += 256) atomicAdd(&bcnt[i], lh[i]);
}

// 3-phase parallel node-count scan -> rowptr[NN+1]
__global__ void k_scan1(const int* __restrict__ ncnt, int* __restrict__ bsum) {
    __shared__ int s[SCAN_B];
    int i = blockIdx.x * SCAN_B + threadIdx.x;
    s[threadIdx.x] = (i < NN) ? ncnt[i] : 0;
    __syncthreads();
    for (int off = SCAN_B / 2; off > 0; off >>= 1) {
        if (threadIdx.x < off) s[threadIdx.x] += s[threadIdx.x + off];
        __syncthreads();
    }
    if (threadIdx.x == 0) bsum[blockIdx.x] = s[0];
}

__global__ void k_scan2(const int* __restrict__ bsum, int* __restrict__ bpref, int* __restrict__ rowptr) {
    if (threadIdx.x == 0 && blockIdx.x == 0) {
        int run = 0;
        for (int b = 0; b < NB_SCAN; ++b) { bpref[b] = run; run += bsum[b]; }
        rowptr[NN] = run;
    }
}

__global__ void k_scan3(const int* __restrict__ ncnt, const int* __restrict__ bpref,
                        int* __restrict__ rowptr) {
    __shared__ int s[SCAN_B];
    int i = blockIdx.x * SCAN_B + threadIdx.x;
    int val = (i < NN) ? ncnt[i] : 0;
    s[threadIdx.x] = val;
    __syncthreads();
    for (int off = 1; off < SCAN_B; off <<= 1) {
        int x = (threadIdx.x >= off) ? s[threadIdx.x - off] : 0;
        __syncthreads();
        s[threadIdx.x] += x;
        __syncthreads();
    }
    if (i < NN) rowptr[i] = bpref[blockIdx.x] + s[threadIdx.x] - val;
}

// bucket scan + parallel tile map build
__global__ __launch_bounds__(1024)
void k_scan_buckets(const int* __restrict__ bcnt, int B, int npc, int SB,
                    const int* __restrict__ rowptr,
                    int* __restrict__ boff, int* __restrict__ tstart,
                    int4* __restrict__ tilemap) {
    __shared__ int s1[MAXB], s2[MAXB];
    __shared__ int e_ex[MAXB + 1], t_ex[MAXB + 1];
    int tid = threadIdx.x;
    int v1 = (tid < B) ? bcnt[tid] : 0;
    int v2 = (v1 + TS - 1) / TS;
    s1[tid] = v1; s2[tid] = v2;
    __syncthreads();
    for (int off = 1; off < MAXB; off <<= 1) {
        int a1 = (tid >= off) ? s1[tid - off] : 0;
        int a2 = (tid >= off) ? s2[tid - off] : 0;
        __syncthreads();
        s1[tid] += a1; s2[tid] += a2;
        __syncthreads();
    }
    if (tid < B) {
        e_ex[tid] = s1[tid] - v1;
        t_ex[tid] = s2[tid] - v2;
        boff[tid] = e_ex[tid];
        tstart[tid] = t_ex[tid];
        if (tid == B - 1) {
            e_ex[B] = s1[tid]; t_ex[B] = s2[tid];
            boff[B] = s1[tid]; tstart[B] = s2[tid];
        }
    }
    __syncthreads();
    int T = t_ex[B];
    for (int t = tid; t < T; t += 1024) {
        int lo = 0, hi = B - 1;
        while (lo < hi) {
            int mid = (lo + hi + 1) >> 1;
            if (t_ex[mid] <= t) lo = mid; else hi = mid - 1;
        }
        int b = lo;
        int tt = t - t_ex[b];
        int v1b = e_ex[b + 1] - e_ex[b];
        int rem = v1b - tt * TS;
        int cnt = rem < TS ? rem : TS;
        int chunk = b / SB;
        int nstart = chunk * npc; if (nstart > NN) nstart = NN;
        tilemap[t] = make_int4(b & (NR - 1), e_ex[b] + tt * TS, cnt, rowptr[nstart]);
    }
}

// scatter: store SOURCE NODE id at bucket-sorted slot
__global__ void k_scatter(const int* __restrict__ rel, const int* __restrict__ dst,
                          const int* __restrict__ src,
                          const int* __restrict__ boff, int* __restrict__ cursor,
                          const int* __restrict__ rowptr, int* __restrict__ ncur,
                          int* __restrict__ srcs, int* __restrict__ dpos,
                          int npc, int nps, int SB, int B) {
    __shared__ int lh[MAXB];
    const int CH = 4096;
    int e0 = blockIdx.x * CH;
    for (int i = threadIdx.x; i < B; i += 256) lh[i] = 0;
    __syncthreads();
    for (int i = threadIdx.x; i < CH; i += 256) {
        int e = e0 + i;
        if (e < NE) atomicAdd(&lh[(dst[e] / npc) * SB + (src[e] / nps) * NR + rel[e]], 1);
    }
    __syncthreads();
    for (int i = threadIdx.x; i < B; i += 256) {
        int c = lh[i];
        lh[i] = (c > 0) ? atomicAdd(&cursor[i], c) : 0;
    }
    __syncthreads();
    for (int i = threadIdx.x; i < CH; i += 256) {
        int e = e0 + i;
        if (e < NE) {
            int d = dst[e];
            int s = src[e];
            int b = (d / npc) * SB + (s / nps) * NR + rel[e];
            int p = boff[b] + atomicAdd(&lh[b], 1);
            int pd = rowptr[d] + atomicAdd(&ncur[d], 1);
            srcs[p] = s;
            dpos[p] = pd;
        }
    }
}

// ---------------- conversions ----------------

__global__ void k_hconv(const float* __restrict__ h, unsigned short* __restrict__ hb, int n4) {
    int i = blockIdx.x * 256 + threadIdx.x;
    if (i < n4) {
        float4 v = reinterpret_cast<const float4*>(h)[i];
        ushort4 o = { f2bf(v.x), f2bf(v.y), f2bf(v.z), f2bf(v.w) };
        reinterpret_cast<ushort4*>(hb)[i] = o;
    }
}

__global__ void k_wconv_all(const float* Wr0, const float* Wr1, const float* Wr2,
                            const float* Wl0, const float* Wl1, const float* Wl2,
                            unsigned short* Wt0, unsigned short* Wt1, unsigned short* Wt2,
                            unsigned short* Wlt0, unsigned short* Wlt1, unsigned short* Wlt2) {
    const float* W; unsigned short* O; int R, Kd, Nd;
    switch (blockIdx.y) {
        case 0:  W = Wr0; O = Wt0;  R = NR; Kd = 128; Nd = 128; break;
        case 1:  W = Wr1; O = Wt1;  R = NR; Kd = 128; Nd = 256; break;
        case 2:  W = Wr2; O = Wt2;  R = NR; Kd = 256; Nd = 128; break;
        case 3:  W = Wl0; O = Wlt0; R = 1;  Kd = 128; Nd = 128; break;
        case 4:  W = Wl1; O = Wlt1; R = 1;  Kd = 128; Nd = 256; break;
        default: W = Wl2; O = Wlt2; R = 1;  Kd = 256; Nd = 128; break;
    }
    int total = R * Kd * Nd;
    for (int i = blockIdx.x * 256 + threadIdx.x; i < total; i += gridDim.x * 256) {
        int r = i / (Kd * Nd);
        int rem = i - r * Kd * Nd;
        int k = rem / Nd;
        int n = rem - k * Nd;
        O[((size_t)r * Nd + n) * Kd + k] = f2bf(W[i]);
    }
}

// ---------------- MFMA dense GEMM (LDS-staged, proven) ----------------

template<int K>
__global__ __launch_bounds__(256, 4)
void k_dense_mfma(const unsigned short* __restrict__ hb,
                  const unsigned short* __restrict__ Wlt,   // [ldn][K] bf16
                  const float* __restrict__ bias,
                  float* __restrict__ outbuf, int ldn) {
    __shared__ __align__(16) unsigned short As[128][72];
    __shared__ __align__(16) unsigned short Bs[128][72];
    const int tid = threadIdx.x;
    const int row0 = blockIdx.x * 128;
    const int colbase = blockIdx.y * 128;
    const int lane = tid & 63, w = tid >> 6;
    const int quad = lane >> 4, col = lane & 15;
    const int srow = tid >> 3, sk = (tid & 7) * 8;

    f32x4 acc[8][2];
#pragma unroll
    for (int i = 0; i < 8; ++i) { acc[i][0] = 0.f; acc[i][1] = 0.f; }

    for (int k0 = 0; k0 < K; k0 += 64) {
        __syncthreads();
#pragma unroll
        for (int pp = 0; pp < 4; ++pp) {
            int rw = pp * 32 + srow;
            int ar = row0 + rw; if (ar >= NN) ar = NN - 1;
            *reinterpret_cast<uint4*>(&As[rw][sk]) =
                *reinterpret_cast<const uint4*>(hb + (size_t)ar * K + k0 + sk);
            *reinterpret_cast<uint4*>(&Bs[rw][sk]) =
                *reinterpret_cast<const uint4*>(Wlt + (size_t)(colbase + rw) * K + k0 + sk);
        }
        __syncthreads();
#pragma unroll
        for (int s = 0; s < 2; ++s) {
            bf16x8 bf0 = *reinterpret_cast<const bf16x8*>(&Bs[w * 32 + col][s * 32 + quad * 8]);
            bf16x8 bf1 = *reinterpret_cast<const bf16x8*>(&Bs[w * 32 + 16 + col][s * 32 + quad * 8]);
#pragma unroll
            for (int rt = 0; rt < 8; ++rt) {
                bf16x8 af = *reinterpret_cast<const bf16x8*>(&As[rt * 16 + col][s * 32 + quad * 8]);
                acc[rt][0] = __builtin_amdgcn_mfma_f32_16x16x32_bf16(af, bf0, acc[rt][0], 0, 0, 0);
                acc[rt][1] = __builtin_amdgcn_mfma_f32_16x16x32_bf16(af, bf1, acc[rt][1], 0, 0, 0);
            }
        }
    }
    float bv0 = bias[colbase + w * 32 + col];
    float bv1 = bias[colbase + w * 32 + 16 + col];
#pragma unroll
    for (int rt = 0; rt < 8; ++rt) {
#pragma unroll
        for (int reg = 0; reg < 4; ++reg) {
            int r = row0 + rt * 16 + quad * 4 + reg;
            if (r < NN) {
                float* dp = outbuf + (size_t)r * ldn + colbase + w * 32;
                dp[col] = acc[rt][0][reg] + bv0;
                dp[16 + col] = acc[rt][1][reg] + bv1;
            }
        }
    }
}

// ---------------- MFMA edge GEMM (round-8 shape, pad 136): 1 tile/block,
// full 128-K A slice in LDS, B direct from global.
// paired=1: gridDim.x covers 2T blocks; blocks 16k+j and 16k+8+j (same XCD
// under round-robin dispatch) process the same tile's two column halves. ----------------

template<int K>
__global__ __launch_bounds__(256, 4)
void k_edge_mfma(const unsigned short* __restrict__ hb,
                 const unsigned short* __restrict__ Wt,   // [NR][ldn][K] bf16
                 int ldn, int colbase, int msgw, int paired,
                 const int* __restrict__ srcs, const int* __restrict__ dpos,
                 const int4* __restrict__ tilemap, const int* __restrict__ tstart,
                 int chunkBase, int SB,
                 unsigned short* __restrict__ msg, int capRows) {
    const int tb0 = tstart[chunkBase];
    const int T = tstart[chunkBase + SB] - tb0;
    int t_lin, cb;
    if (paired) {
        t_lin = ((blockIdx.x >> 4) << 3) | (blockIdx.x & 7);
        cb = ((blockIdx.x >> 3) & 1) * 128;
    } else {
        t_lin = blockIdx.x;
        cb = colbase;
    }
    if (t_lin >= T) return;
    const int4 tm = tilemap[tb0 + t_lin];
    const int r = tm.x, e0 = tm.y, cnt = tm.z, cES = tm.w;

    __shared__ __align__(16) unsigned short As[128][136];
    __shared__ int s_src[TS], s_out[TS];
    const int tid = threadIdx.x;
    if (tid < TS) {
        int ei = e0 + (tid < cnt ? tid : cnt - 1);
        s_src[tid] = srcs[ei];
        int row = dpos[ei] - cES;
        s_out[tid] = (tid < cnt && row < capRows) ? row : -1;
    }
    __syncthreads();

    const unsigned short* Wb = Wt + ((size_t)r * ldn + cb) * K;
    const int lane = tid & 63, w = tid >> 6;
    const int quad = lane >> 4, col = lane & 15;
    const int asr = tid >> 4, ask = (tid & 15) * 8;

    f32x4 acc[8][2];
#pragma unroll
    for (int i = 0; i < 8; ++i) { acc[i][0] = 0.f; acc[i][1] = 0.f; }

    for (int kk = 0; kk < K; kk += 128) {
        if (kk) __syncthreads();
#pragma unroll
        for (int q = 0; q < 8; ++q) {
            int rw = q * 16 + asr;
            *reinterpret_cast<uint4*>(&As[rw][ask]) =
                *reinterpret_cast<const uint4*>(hb + (size_t)s_src[rw] * K + kk + ask);
        }
        __syncthreads();
#pragma unroll
        for (int k32 = 0; k32 < 4; ++k32) {
            bf16x8 bf0 = *reinterpret_cast<const bf16x8*>(
                Wb + (size_t)(w * 32 + col) * K + kk + k32 * 32 + quad * 8);
            bf16x8 bf1 = *reinterpret_cast<const bf16x8*>(
                Wb + (size_t)(w * 32 + 16 + col) * K + kk + k32 * 32 + quad * 8);
#pragma unroll
            for (int rt = 0; rt < 8; ++rt) {
                bf16x8 af = *reinterpret_cast<const bf16x8*>(&As[rt * 16 + col][k32 * 32 + quad * 8]);
                acc[rt][0] = __builtin_amdgcn_mfma_f32_16x16x32_bf16(af, bf0, acc[rt][0], 0, 0, 0);
                acc[rt][1] = __builtin_amdgcn_mfma_f32_16x16x32_bf16(af, bf1, acc[rt][1], 0, 0, 0);
            }
        }
    }
#pragma unroll
    for (int rt = 0; rt < 8; ++rt) {
#pragma unroll
        for (int reg = 0; reg < 4; ++reg) {
            int m = rt * 16 + quad * 4 + reg;
            int o = s_out[m];
            if (o >= 0) {
                unsigned short* dp = msg + (size_t)o * msgw + cb + w * 32;
                dp[col] = f2bf(acc[rt][0][reg]);
                dp[16 + col] = f2bf(acc[rt][1][reg]);
            }
        }
    }
}

// segmented reduce: one wave per node, 4-way unrolled row loads.
// grid.y selects a 128-col slice (offset y*128 applied to msg + all outputs).
__global__ __launch_bounds__(256)
void k_reduce(const unsigned short* __restrict__ msg, int msgw,
              const float* __restrict__ selfb, int ld_self, int co_self,
              unsigned short* __restrict__ out_bf, int ld_bf, int co_bf,
              float* __restrict__ out_f32, int ld_f32, int co_f32,
              const int* __restrict__ rowptr, int n0, int npc, int capRows) {
    int idx = blockIdx.x * 4 + (threadIdx.x >> 6);
    int n = n0 + idx;
    if (idx >= npc || n >= NN) return;
    int lane = threadIdx.x & 63;
    int cofs = blockIdx.y * 128;
    int cES = rowptr[n0];
    float2 acc = *reinterpret_cast<const float2*>(selfb + (size_t)n * ld_self + co_self + cofs + lane * 2);
    int j0 = rowptr[n], j1 = rowptr[n + 1];
    int jcap = cES + capRows; if (j1 > jcap) j1 = jcap;
    const int stride = msgw >> 1;
    const unsigned int* mp = reinterpret_cast<const unsigned int*>(msg) + (cofs >> 1) + lane;
    int j = j0;
    for (; j + 4 <= j1; j += 4) {
        unsigned int m0 = mp[(size_t)(j + 0 - cES) * stride];
        unsigned int m1 = mp[(size_t)(j + 1 - cES) * stride];
        unsigned int m2 = mp[(size_t)(j + 2 - cES) * stride];
        unsigned int m3 = mp[(size_t)(j + 3 - cES) * stride];
        acc.x += bf2f((unsigned short)(m0 & 0xffffu)) + bf2f((unsigned short)(m1 & 0xffffu))
               + bf2f((unsigned short)(m2 & 0xffffu)) + bf2f((unsigned short)(m3 & 0xffffu));
        acc.y += bf2f((unsigned short)(m0 >> 16)) + bf2f((unsigned short)(m1 >> 16))
               + bf2f((unsigned short)(m2 >> 16)) + bf2f((unsigned short)(m3 >> 16));
    }
    for (; j < j1; ++j) {
        unsigned int m = mp[(size_t)(j - cES) * stride];
        acc.x += bf2f((unsigned short)(m & 0xffffu));
        acc.y += bf2f((unsigned short)(m >> 16));
    }
    acc.x = acc.x > 0.f ? acc.x : 0.f;
    acc.y = acc.y > 0.f ? acc.y : 0.f;
    if (out_bf) {
        unsigned int o = (unsigned int)f2bf(acc.x) | ((unsigned int)f2bf(acc.y) << 16);
        *reinterpret_cast<unsigned int*>(out_bf + (size_t)n * ld_bf + co_bf + cofs + lane * 2) = o;
    }
    if (out_f32) {
        *reinterpret_cast<float2*>(out_f32 + (size_t)n * ld_f32 + co_f32 + cofs + lane * 2) = acc;
    }
}

// ---------------- pooling / fused MLP head ----------------

__global__ void k_pool(const float* __restrict__ h, const int* __restrict__ gid,
                       float* __restrict__ hg, float* __restrict__ gcnt) {
    const int c = threadIdx.x;  // 128
    int n0 = blockIdx.x * 64;
    if (n0 >= NN) return;
    int end = n0 + 64; if (end > NN) end = NN;
    int cur = gid[n0];
    float run = 0.f, crun = 0.f;
    for (int n = n0; n < end; ++n) {
        int g = gid[n];
        if (g != cur) {
            atomicAdd(&hg[cur * 128 + c], run);
            if (c == 0) atomicAdd(&gcnt[cur], crun);
            run = 0.f; crun = 0.f; cur = g;
        }
        run += h[(size_t)n * 128 + c];
        crun += 1.f;
    }
    atomicAdd(&hg[cur * 128 + c], run);
    if (c == 0) atomicAdd(&gcnt[cur], crun);
}

__global__ __launch_bounds__(256)
void k_head(const float* __restrict__ hg, const float* __restrict__ gcnt,
            const float* __restrict__ Wh0, const float* __restrict__ bh0,
            const float* __restrict__ Wh1, const float* __restrict__ bh1,
            const float* __restrict__ Wh2, const float* __restrict__ bh2,
            const float* __restrict__ Wc, const float* __restrict__ bc,
            float* __restrict__ out) {
    __shared__ float x0[128], x1[128], x2[256], x3[128], sl[8];
    int g = blockIdx.x, t = threadIdx.x;
    if (t < 128) {
        float c = gcnt[g];
        x0[t] = hg[g * 128 + t] / (c > 1.f ? c : 1.f);
    }
    __syncthreads();
    if (t < 128) {
        float a = bh0[t];
        for (int k = 0; k < 128; ++k) a += x0[k] * Wh0[k * 128 + t];
        x1[t] = a > 0.f ? a : 0.f;
    }
    __syncthreads();
    {
        float a = bh1[t];
        for (int k = 0; k < 128; ++k) a += x1[k] * Wh1[k * 256 + t];
        x2[t] = a > 0.f ? a : 0.f;
    }
    __syncthreads();
    if (t < 128) {
        float a = bh2[t];
        for (int k = 0; k < 256; ++k) a += x2[k] * Wh2[k * 128 + t];
        x3[t] = a > 0.f ? a : 0.f;
    }
    __syncthreads();
    if (t < 8) {
        float a = bc[t];
        for (int k = 0; k < 128; ++k) a += x3[k] * Wc[k * 8 + t];
        sl[t] = a;
    }
    __syncthreads();
    if (t == 0) {
        float m = sl[0];
        for (int c = 1; c < 8; ++c) m = sl[c] > m ? sl[c] : m;
        float s = 0.f, e[8];
        for (int c = 0; c < 8; ++c) { e[c] = expf(sl[c] - m); s += e[c]; }
        for (int c = 0; c < 8; ++c) out[g * 8 + c] = e[c] / s;
    }
}

// ---------------- launcher ----------------

extern "C" void kernel_launch(void* const* d_in, const int* in_sizes, int n_in,
                              void* d_out, int out_size, void* d_ws, size_t ws_size,
                              hipStream_t stream) {
    const float* h0   = (const float*)d_in[0];
    const int* src    = (const int*)d_in[1];
    const int* dst    = (const int*)d_in[2];
    const int* rel    = (const int*)d_in[3];
    const int* gid    = (const int*)d_in[4];
    const float* Wr0  = (const float*)d_in[5];
    const float* Wl0  = (const float*)d_in[6];
    const float* b0   = (const float*)d_in[7];
    const float* Wr1  = (const float*)d_in[8];
    const float* Wl1  = (const float*)d_in[9];
    const float* b1   = (const float*)d_in[10];
    const float* Wr2  = (const float*)d_in[11];
    const float* Wl2  = (const float*)d_in[12];
    const float* b2   = (const float*)d_in[13];
    const float* Wh0  = (const float*)d_in[14];
    const float* bh0  = (const float*)d_in[15];
    const float* Wh1  = (const float*)d_in[16];
    const float* bh1  = (const float*)d_in[17];
    const float* Wh2  = (const float*)d_in[18];
    const float* bh2  = (const float*)d_in[19];
    const float* Wc   = (const float*)d_in[20];
    const float* bc   = (const float*)d_in[21];
    float* out = (float*)d_out;

    // workspace layout (256B-aligned blocks); zero-init arrays contiguous
    char* p = (char*)d_ws;
    auto alloc = [&](size_t bytes) { char* q = p; p += (bytes + 255) & ~(size_t)255; return q; };
    float* bufS  = (float*)alloc((size_t)NN * 256 * 4);
    unsigned short* hbA = (unsigned short*)alloc((size_t)NN * 256 * 2);
    unsigned short* hbB = (unsigned short*)alloc((size_t)NN * 128 * 2);
    unsigned short* Wt0 = (unsigned short*)alloc((size_t)NR * 128 * 128 * 2);
    unsigned short* Wt1 = (unsigned short*)alloc((size_t)NR * 256 * 128 * 2);
    unsigned short* Wt2 = (unsigned short*)alloc((size_t)NR * 128 * 256 * 2);
    unsigned short* Wlt0 = (unsigned short*)alloc((size_t)128 * 128 * 2);
    unsigned short* Wlt1 = (unsigned short*)alloc((size_t)256 * 128 * 2);
    unsigned short* Wlt2 = (unsigned short*)alloc((size_t)128 * 256 * 2);
    int* srcs    = (int*)alloc((size_t)NE * 4);
    int* dpos    = (int*)alloc((size_t)NE * 4);
    int* rowptr  = (int*)alloc((size_t)(NN + 1) * 4);
    int* bsum    = (int*)alloc(NB_SCAN * 4);
    int* bpref   = (int*)alloc(NB_SCAN * 4);
    int* boff    = (int*)alloc((MAXB + 1) * 4);
    int* tstart  = (int*)alloc((MAXB + 1) * 4);
    int4* tilemap = (int4*)alloc((size_t)(NE / TS + MAXB + 64) * 16);
    // ---- zero-init region (one memset) ----
    char* zbase  = p;
    int* bcnt    = (int*)alloc(MAXB * 4);
    int* cursor  = (int*)alloc(MAXB * 4);
    int* ncnt    = (int*)alloc((size_t)NN * 4);
    int* ncur    = (int*)alloc((size_t)NN * 4);
    float* hg    = (float*)alloc((size_t)NG * 128 * 4);
    float* gcnt  = (float*)alloc(NG * 4);
    size_t zlen  = (size_t)(p - zbase);
    unsigned short* msg = (unsigned short*)p;

    long long avail = (long long)ws_size - (long long)(p - (char*)d_ws);
    if (avail < (1 << 20)) avail = (1 << 20);
    long long capR64 = avail / 256;                 // bf16 rows of 128
    int C = 64;
    for (int c = 1; c <= 64; ++c) {
        double need = (double)NE / c * 1.15 + 4096.0;
        if ((double)capR64 >= need) { C = c; break; }
    }
    int npc = (NN + C - 1) / C;
    int S = MAXB / (C * NR); if (S < 1) S = 1;
    int SB = S * NR;
    int B = C * SB;
    int nps = (NN + S - 1) / S;
    int capRows = capR64 > 2000000000LL ? 2000000000 : (int)capR64;
    int TPC = (int)((double)NE / C * 1.15 / TS) + SB + 16;
    int RDB = (npc + 3) / 4;
    // fused layer-1 (256-wide msg) if capacity allows
    int fused = (C == 1 && (double)avail >= (double)NE * 1.15 * 512.0 + 2097152.0) ? 1 : 0;
    int capRows256 = (int)(avail / 512);

    // preprocessing
    hipMemsetAsync(zbase, 0, zlen, stream);
    k_hist<<<256, 256, 0, stream>>>(rel, dst, src, bcnt, ncnt, npc, nps, SB, B);
    k_scan1<<<NB_SCAN, SCAN_B, 0, stream>>>(ncnt, bsum);
    k_scan2<<<1, 64, 0, stream>>>(bsum, bpref, rowptr);
    k_scan3<<<NB_SCAN, SCAN_B, 0, stream>>>(ncnt, bpref, rowptr);
    k_scan_buckets<<<1, MAXB, 0, stream>>>(bcnt, B, npc, SB, rowptr, boff, tstart, tilemap);
    k_scatter<<<(NE + 4095) / 4096, 256, 0, stream>>>(rel, dst, src, boff, cursor, rowptr, ncur, srcs, dpos, npc, nps, SB, B);

    k_hconv<<<(NN * 128 / 4 + 255) / 256, 256, 0, stream>>>(h0, hbA, NN * 128 / 4);
    k_wconv_all<<<dim3(512, 6), 256, 0, stream>>>(Wr0, Wr1, Wr2, Wl0, Wl1, Wl2,
                                                  Wt0, Wt1, Wt2, Wlt0, Wlt1, Wlt2);

    const int RB = (NN + TS - 1) / TS;  // 391

    // ---- layer 0: 128 -> 128 (in hbA[ld128], out hbB bf16[ld128]) ----
    k_dense_mfma<128><<<dim3(RB, 1), 256, 0, stream>>>(hbA, Wlt0, b0, bufS, 128);
    for (int c = 0; c < C; ++c) {
        k_edge_mfma<128><<<TPC, 256, 0, stream>>>(hbA, Wt0, 128, 0, 128, 0, srcs, dpos, tilemap, tstart, c * SB, SB, msg, capRows);
        k_reduce<<<dim3(RDB, 1), 256, 0, stream>>>(msg, 128, bufS, 128, 0, hbB, 128, 0, (float*)nullptr, 0, 0, rowptr, c * npc, npc, capRows);
    }

    // ---- layer 1: 128 -> 256 (in hbB[ld128], out hbA bf16[ld256]) ----
    k_dense_mfma<128><<<dim3(RB, 2), 256, 0, stream>>>(hbB, Wlt1, b1, bufS, 256);
    if (fused) {
        // single dispatch, both column halves; same-XCD pairing of halves per tile
        k_edge_mfma<128><<<2 * TPC, 256, 0, stream>>>(hbB, Wt1, 256, 0, 256, 1, srcs, dpos, tilemap, tstart, 0, SB, msg, capRows256);
        k_reduce<<<dim3(RDB, 2), 256, 0, stream>>>(msg, 256, bufS, 256, 0, hbA, 256, 0, (float*)nullptr, 0, 0, rowptr, 0, npc, capRows256);
    } else {
        for (int half = 0; half < 2; ++half) {
            for (int c = 0; c < C; ++c) {
                k_edge_mfma<128><<<TPC, 256, 0, stream>>>(hbB, Wt1, 256, half * 128, 128, 0, srcs, dpos, tilemap, tstart, c * SB, SB, msg, capRows);
                k_reduce<<<dim3(RDB, 1), 256, 0, stream>>>(msg, 128, bufS, 256, half * 128, hbA, 256, half * 128, (float*)nullptr, 0, 0, rowptr, c * npc, npc, capRows);
            }
        }
    }

    // ---- layer 2: 256 -> 128 (in hbA[ld256], out bufS fp32[ld128] in place) ----
    k_dense_mfma<256><<<dim3(RB, 1), 256, 0, stream>>>(hbA, Wlt2, b2, bufS, 128);
    for (int c = 0; c < C; ++c) {
        k_edge_mfma<256><<<TPC, 256, 0, stream>>>(hbA, Wt2, 128, 0, 128, 0, srcs, dpos, tilemap, tstart, c * SB, SB, msg, capRows);
        k_reduce<<<dim3(RDB, 1), 256, 0, stream>>>(msg, 128, bufS, 128, 0, (unsigned short*)nullptr, 0, 0, bufS, 128, 0, rowptr, c * npc, npc, capRows);
    }

    // mean pooling + fused MLP head
    k_pool<<<(NN + 63) / 64, 128, 0, stream>>>(bufS, gid, hg, gcnt);
    k_head<<<NG, 256, 0, stream>>>(hg, gcnt, Wh0, bh0, Wh1, bh1, Wh2, bh2, Wc, bc, out);
}

// Round 15
// 737.478 us; speedup vs baseline: 1.0207x; 1.0195x over previous
//
#include <hip/hip_runtime.h>
#include <stdint.h>

#define NN 50000
#define NE 600000
#define NR 16
#define NG 128
#define TS 128
#define SCAN_B 512
#define NB_SCAN ((NN + SCAN_B - 1) / SCAN_B)   // 98
#define MAXB 1024

typedef short bf16x8 __attribute__((ext_vector_type(8)));
typedef float f32x4 __attribute__((ext_vector_type(4)));

static __device__ __forceinline__ unsigned short f2bf(float x) {
    unsigned int b = __float_as_uint(x);
    b += 0x7FFFu + ((b >> 16) & 1u);
    return (unsigned short)(b >> 16);
}
static __device__ __forceinline__ float bf2f(unsigned short u) {
    return __uint_as_float(((unsigned int)u) << 16);
}

// ---------------- histograms / sort ----------------
// bucket key = dchunk*SB + (src/nps)*NR + rel   (SB = S*NR; rel in low bits)

__global__ void k_hist(const int* __restrict__ rel, const int* __restrict__ dst,
                       const int* __restrict__ src,
                       int* __restrict__ bcnt,
                       int npc, int nps, int SB, int B) {
    __shared__ int lh[MAXB];
    for (int i = threadIdx.x; i < B; i += 256) lh[i] = 0;
    __syncthreads();
    for (int e = blockIdx.x * blockDim.x + threadIdx.x; e < NE; e += gridDim.x * blockDim.x) {
        int key = (dst[e] / npc) * SB + (src[e] / nps) * NR + rel[e];
        atomicAdd(&lh[key], 1);
    }
    __syncthreads();
    for (int i = threadIdx.x; i < B; i += 256) atomicAdd(&bcnt[i], lh[i]);
}

// bucket prefix scans only (tilemap built later, after rowptr)
__global__ __launch_bounds__(1024)
void k_scanb(const int* __restrict__ bcnt, int B,
             int* __restrict__ boff, int* __restrict__ tstart) {
    __shared__ int s1[MAXB], s2[MAXB];
    int tid = threadIdx.x;
    int v1 = (tid < B) ? bcnt[tid] : 0;
    int v2 = (v1 + TS - 1) / TS;
    s1[tid] = v1; s2[tid] = v2;
    __syncthreads();
    for (int off = 1; off < MAXB; off <<= 1) {
        int a1 = (tid >= off) ? s1[tid - off] : 0;
        int a2 = (tid >= off) ? s2[tid - off] : 0;
        __syncthreads();
        s1[tid] += a1; s2[tid] += a2;
        __syncthreads();
    }
    if (tid < B) {
        boff[tid] = s1[tid] - v1;
        tstart[tid] = s2[tid] - v2;
        if (tid == B - 1) { boff[B] = s1[tid]; tstart[B] = s2[tid]; }
    }
}

// scatter: store src node id, dst node id, and LOCAL per-dst rank (no rowptr dep)
__global__ void k_scatter(const int* __restrict__ rel, const int* __restrict__ dst,
                          const int* __restrict__ src,
                          const int* __restrict__ boff, int* __restrict__ cursor,
                          int* __restrict__ ncur,
                          int* __restrict__ srcs, int* __restrict__ dstv, int* __restrict__ dpos,
                          int npc, int nps, int SB, int B) {
    __shared__ int lh[MAXB];
    const int CH = 4096;
    int e0 = blockIdx.x * CH;
    for (int i = threadIdx.x; i < B; i += 256) lh[i] = 0;
    __syncthreads();
    for (int i = threadIdx.x; i < CH; i += 256) {
        int e = e0 + i;
        if (e < NE) atomicAdd(&lh[(dst[e] / npc) * SB + (src[e] / nps) * NR + rel[e]], 1);
    }
    __syncthreads();
    for (int i = threadIdx.x; i < B; i += 256) {
        int c = lh[i];
        lh[i] = (c > 0) ? atomicAdd(&cursor[i], c) : 0;
    }
    __syncthreads();
    for (int i = threadIdx.x; i < CH; i += 256) {
        int e = e0 + i;
        if (e < NE) {
            int d = dst[e];
            int s = src[e];
            int b = (d / npc) * SB + (s / nps) * NR + rel[e];
            int p = boff[b] + atomicAdd(&lh[b], 1);
            srcs[p] = s;
            dstv[p] = d;
            dpos[p] = atomicAdd(&ncur[d], 1);   // local rank; rowptr added in k_fix
        }
    }
}

// 3-phase parallel node-count scan (on ncur, post-scatter) -> rowptr[NN+1]
__global__ void k_scan1(const int* __restrict__ ncnt, int* __restrict__ bsum) {
    __shared__ int s[SCAN_B];
    int i = blockIdx.x * SCAN_B + threadIdx.x;
    s[threadIdx.x] = (i < NN) ? ncnt[i] : 0;
    __syncthreads();
    for (int off = SCAN_B / 2; off > 0; off >>= 1) {
        if (threadIdx.x < off) s[threadIdx.x] += s[threadIdx.x + off];
        __syncthreads();
    }
    if (threadIdx.x == 0) bsum[blockIdx.x] = s[0];
}

__global__ void k_scan2(const int* __restrict__ bsum, int* __restrict__ bpref, int* __restrict__ rowptr) {
    if (threadIdx.x == 0 && blockIdx.x == 0) {
        int run = 0;
        for (int b = 0; b < NB_SCAN; ++b) { bpref[b] = run; run += bsum[b]; }
        rowptr[NN] = run;
    }
}

__global__ void k_scan3(const int* __restrict__ ncnt, const int* __restrict__ bpref,
                        int* __restrict__ rowptr) {
    __shared__ int s[SCAN_B];
    int i = blockIdx.x * SCAN_B + threadIdx.x;
    int val = (i < NN) ? ncnt[i] : 0;
    s[threadIdx.x] = val;
    __syncthreads();
    for (int off = 1; off < SCAN_B; off <<= 1) {
        int x = (threadIdx.x >= off) ? s[threadIdx.x - off] : 0;
        __syncthreads();
        s[threadIdx.x] += x;
        __syncthreads();
    }
    if (i < NN) rowptr[i] = bpref[blockIdx.x] + s[threadIdx.x] - val;
}

// dpos[p] += rowptr[dstv[p]]  (plain loads, no atomics)
__global__ void k_fix(const int* __restrict__ dstv, const int* __restrict__ rowptr,
                      int* __restrict__ dpos) {
    int p = blockIdx.x * 256 + threadIdx.x;
    if (p < NE) dpos[p] += rowptr[dstv[p]];
}

// parallel tile map build (needs rowptr)
__global__ __launch_bounds__(1024)
void k_tilemap(const int* __restrict__ boff, const int* __restrict__ tstart,
               int B, int npc, int SB,
               const int* __restrict__ rowptr, int4* __restrict__ tilemap) {
    __shared__ int e_ex[MAXB + 1], t_ex[MAXB + 1];
    int tid = threadIdx.x;
    for (int i = tid; i <= B; i += 1024) { e_ex[i] = boff[i]; t_ex[i] = tstart[i]; }
    __syncthreads();
    int T = t_ex[B];
    for (int t = tid; t < T; t += 1024) {
        int lo = 0, hi = B - 1;
        while (lo < hi) {
            int mid = (lo + hi + 1) >> 1;
            if (t_ex[mid] <= t) lo = mid; else hi = mid - 1;
        }
        int b = lo;
        int tt = t - t_ex[b];
        int v1b = e_ex[b + 1] - e_ex[b];
        int rem = v1b - tt * TS;
        int cnt = rem < TS ? rem : TS;
        int chunk = b / SB;
        int nstart = chunk * npc; if (nstart > NN) nstart = NN;
        tilemap[t] = make_int4(b & (NR - 1), e_ex[b] + tt * TS, cnt, rowptr[nstart]);
    }
}

// ---------------- conversions ----------------

__global__ void k_hconv(const float* __restrict__ h, unsigned short* __restrict__ hb, int n4) {
    int i = blockIdx.x * 256 + threadIdx.x;
    if (i < n4) {
        float4 v = reinterpret_cast<const float4*>(h)[i];
        ushort4 o = { f2bf(v.x), f2bf(v.y), f2bf(v.z), f2bf(v.w) };
        reinterpret_cast<ushort4*>(hb)[i] = o;
    }
}

__global__ void k_wconv_all(const float* Wr0, const float* Wr1, const float* Wr2,
                            const float* Wl0, const float* Wl1, const float* Wl2,
                            unsigned short* Wt0, unsigned short* Wt1, unsigned short* Wt2,
                            unsigned short* Wlt0, unsigned short* Wlt1, unsigned short* Wlt2) {
    const float* W; unsigned short* O; int R, Kd, Nd;
    switch (blockIdx.y) {
        case 0:  W = Wr0; O = Wt0;  R = NR; Kd = 128; Nd = 128; break;
        case 1:  W = Wr1; O = Wt1;  R = NR; Kd = 128; Nd = 256; break;
        case 2:  W = Wr2; O = Wt2;  R = NR; Kd = 256; Nd = 128; break;
        case 3:  W = Wl0; O = Wlt0; R = 1;  Kd = 128; Nd = 128; break;
        case 4:  W = Wl1; O = Wlt1; R = 1;  Kd = 128; Nd = 256; break;
        default: W = Wl2; O = Wlt2; R = 1;  Kd = 256; Nd = 128; break;
    }
    int total = R * Kd * Nd;
    for (int i = blockIdx.x * 256 + threadIdx.x; i < total; i += gridDim.x * 256) {
        int r = i / (Kd * Nd);
        int rem = i - r * Kd * Nd;
        int k = rem / Nd;
        int n = rem - k * Nd;
        O[((size_t)r * Nd + n) * Kd + k] = f2bf(W[i]);
    }
}

// ---------------- MFMA dense GEMM (LDS-staged, proven) ----------------

template<int K>
__global__ __launch_bounds__(256, 4)
void k_dense_mfma(const unsigned short* __restrict__ hb,
                  const unsigned short* __restrict__ Wlt,   // [ldn][K] bf16
                  const float* __restrict__ bias,
                  float* __restrict__ outbuf, int ldn) {
    __shared__ __align__(16) unsigned short As[128][72];
    __shared__ __align__(16) unsigned short Bs[128][72];
    const int tid = threadIdx.x;
    const int row0 = blockIdx.x * 128;
    const int colbase = blockIdx.y * 128;
    const int lane = tid & 63, w = tid >> 6;
    const int quad = lane >> 4, col = lane & 15;
    const int srow = tid >> 3, sk = (tid & 7) * 8;

    f32x4 acc[8][2];
#pragma unroll
    for (int i = 0; i < 8; ++i) { acc[i][0] = 0.f; acc[i][1] = 0.f; }

    for (int k0 = 0; k0 < K; k0 += 64) {
        __syncthreads();
#pragma unroll
        for (int pp = 0; pp < 4; ++pp) {
            int rw = pp * 32 + srow;
            int ar = row0 + rw; if (ar >= NN) ar = NN - 1;
            *reinterpret_cast<uint4*>(&As[rw][sk]) =
                *reinterpret_cast<const uint4*>(hb + (size_t)ar * K + k0 + sk);
            *reinterpret_cast<uint4*>(&Bs[rw][sk]) =
                *reinterpret_cast<const uint4*>(Wlt + (size_t)(colbase + rw) * K + k0 + sk);
        }
        __syncthreads();
#pragma unroll
        for (int s = 0; s < 2; ++s) {
            bf16x8 bf0 = *reinterpret_cast<const bf16x8*>(&Bs[w * 32 + col][s * 32 + quad * 8]);
            bf16x8 bf1 = *reinterpret_cast<const bf16x8*>(&Bs[w * 32 + 16 + col][s * 32 + quad * 8]);
#pragma unroll
            for (int rt = 0; rt < 8; ++rt) {
                bf16x8 af = *reinterpret_cast<const bf16x8*>(&As[rt * 16 + col][s * 32 + quad * 8]);
                acc[rt][0] = __builtin_amdgcn_mfma_f32_16x16x32_bf16(af, bf0, acc[rt][0], 0, 0, 0);
                acc[rt][1] = __builtin_amdgcn_mfma_f32_16x16x32_bf16(af, bf1, acc[rt][1], 0, 0, 0);
            }
        }
    }
    float bv0 = bias[colbase + w * 32 + col];
    float bv1 = bias[colbase + w * 32 + 16 + col];
#pragma unroll
    for (int rt = 0; rt < 8; ++rt) {
#pragma unroll
        for (int reg = 0; reg < 4; ++reg) {
            int r = row0 + rt * 16 + quad * 4 + reg;
            if (r < NN) {
                float* dp = outbuf + (size_t)r * ldn + colbase + w * 32;
                dp[col] = acc[rt][0][reg] + bv0;
                dp[16 + col] = acc[rt][1][reg] + bv1;
            }
        }
    }
}

// ---------------- MFMA edge GEMM (round-8 shape, pad 136): 1 tile/block,
// full 128-K A slice in LDS, B direct from global.
// paired=1: blocks 16k+j and 16k+8+j (same XCD under round-robin dispatch)
// process the same tile's two column halves. ----------------

template<int K>
__global__ __launch_bounds__(256, 4)
void k_edge_mfma(const unsigned short* __restrict__ hb,
                 const unsigned short* __restrict__ Wt,   // [NR][ldn][K] bf16
                 int ldn, int colbase, int msgw, int paired,
                 const int* __restrict__ srcs, const int* __restrict__ dpos,
                 const int4* __restrict__ tilemap, const int* __restrict__ tstart,
                 int chunkBase, int SB,
                 unsigned short* __restrict__ msg, int capRows) {
    const int tb0 = tstart[chunkBase];
    const int T = tstart[chunkBase + SB] - tb0;
    int t_lin, cb;
    if (paired) {
        t_lin = ((blockIdx.x >> 4) << 3) | (blockIdx.x & 7);
        cb = ((blockIdx.x >> 3) & 1) * 128;
    } else {
        t_lin = blockIdx.x;
        cb = colbase;
    }
    if (t_lin >= T) return;
    const int4 tm = tilemap[tb0 + t_lin];
    const int r = tm.x, e0 = tm.y, cnt = tm.z, cES = tm.w;

    __shared__ __align__(16) unsigned short As[128][136];
    __shared__ int s_src[TS], s_out[TS];
    const int tid = threadIdx.x;
    if (tid < TS) {
        int ei = e0 + (tid < cnt ? tid : cnt - 1);
        s_src[tid] = srcs[ei];
        int row = dpos[ei] - cES;
        s_out[tid] = (tid < cnt && row < capRows) ? row : -1;
    }
    __syncthreads();

    const unsigned short* Wb = Wt + ((size_t)r * ldn + cb) * K;
    const int lane = tid & 63, w = tid >> 6;
    const int quad = lane >> 4, col = lane & 15;
    const int asr = tid >> 4, ask = (tid & 15) * 8;

    f32x4 acc[8][2];
#pragma unroll
    for (int i = 0; i < 8; ++i) { acc[i][0] = 0.f; acc[i][1] = 0.f; }

    for (int kk = 0; kk < K; kk += 128) {
        if (kk) __syncthreads();
#pragma unroll
        for (int q = 0; q < 8; ++q) {
            int rw = q * 16 + asr;
            *reinterpret_cast<uint4*>(&As[rw][ask]) =
                *reinterpret_cast<const uint4*>(hb + (size_t)s_src[rw] * K + kk + ask);
        }
        __syncthreads();
#pragma unroll
        for (int k32 = 0; k32 < 4; ++k32) {
            bf16x8 bf0 = *reinterpret_cast<const bf16x8*>(
                Wb + (size_t)(w * 32 + col) * K + kk + k32 * 32 + quad * 8);
            bf16x8 bf1 = *reinterpret_cast<const bf16x8*>(
                Wb + (size_t)(w * 32 + 16 + col) * K + kk + k32 * 32 + quad * 8);
#pragma unroll
            for (int rt = 0; rt < 8; ++rt) {
                bf16x8 af = *reinterpret_cast<const bf16x8*>(&As[rt * 16 + col][k32 * 32 + quad * 8]);
                acc[rt][0] = __builtin_amdgcn_mfma_f32_16x16x32_bf16(af, bf0, acc[rt][0], 0, 0, 0);
                acc[rt][1] = __builtin_amdgcn_mfma_f32_16x16x32_bf16(af, bf1, acc[rt][1], 0, 0, 0);
            }
        }
    }
#pragma unroll
    for (int rt = 0; rt < 8; ++rt) {
#pragma unroll
        for (int reg = 0; reg < 4; ++reg) {
            int m = rt * 16 + quad * 4 + reg;
            int o = s_out[m];
            if (o >= 0) {
                unsigned short* dp = msg + (size_t)o * msgw + cb + w * 32;
                dp[col] = f2bf(acc[rt][0][reg]);
                dp[16 + col] = f2bf(acc[rt][1][reg]);
            }
        }
    }
}

// segmented reduce: one wave per node, 4-way unrolled row loads.
// grid.y selects a 128-col slice (offset y*128 applied to msg + all outputs).
__global__ __launch_bounds__(256)
void k_reduce(const unsigned short* __restrict__ msg, int msgw,
              const float* __restrict__ selfb, int ld_self, int co_self,
              unsigned short* __restrict__ out_bf, int ld_bf, int co_bf,
              float* __restrict__ out_f32, int ld_f32, int co_f32,
              const int* __restrict__ rowptr, int n0, int npc, int capRows) {
    int idx = blockIdx.x * 4 + (threadIdx.x >> 6);
    int n = n0 + idx;
    if (idx >= npc || n >= NN) return;
    int lane = threadIdx.x & 63;
    int cofs = blockIdx.y * 128;
    int cES = rowptr[n0];
    float2 acc = *reinterpret_cast<const float2*>(selfb + (size_t)n * ld_self + co_self + cofs + lane * 2);
    int j0 = rowptr[n], j1 = rowptr[n + 1];
    int jcap = cES + capRows; if (j1 > jcap) j1 = jcap;
    const int stride = msgw >> 1;
    const unsigned int* mp = reinterpret_cast<const unsigned int*>(msg) + (cofs >> 1) + lane;
    int j = j0;
    for (; j + 4 <= j1; j += 4) {
        unsigned int m0 = mp[(size_t)(j + 0 - cES) * stride];
        unsigned int m1 = mp[(size_t)(j + 1 - cES) * stride];
        unsigned int m2 = mp[(size_t)(j + 2 - cES) * stride];
        unsigned int m3 = mp[(size_t)(j + 3 - cES) * stride];
        acc.x += bf2f((unsigned short)(m0 & 0xffffu)) + bf2f((unsigned short)(m1 & 0xffffu))
               + bf2f((unsigned short)(m2 & 0xffffu)) + bf2f((unsigned short)(m3 & 0xffffu));
        acc.y += bf2f((unsigned short)(m0 >> 16)) + bf2f((unsigned short)(m1 >> 16))
               + bf2f((unsigned short)(m2 >> 16)) + bf2f((unsigned short)(m3 >> 16));
    }
    for (; j < j1; ++j) {
        unsigned int m = mp[(size_t)(j - cES) * stride];
        acc.x += bf2f((unsigned short)(m & 0xffffu));
        acc.y += bf2f((unsigned short)(m >> 16));
    }
    acc.x = acc.x > 0.f ? acc.x : 0.f;
    acc.y = acc.y > 0.f ? acc.y : 0.f;
    if (out_bf) {
        unsigned int o = (unsigned int)f2bf(acc.x) | ((unsigned int)f2bf(acc.y) << 16);
        *reinterpret_cast<unsigned int*>(out_bf + (size_t)n * ld_bf + co_bf + cofs + lane * 2) = o;
    }
    if (out_f32) {
        *reinterpret_cast<float2*>(out_f32 + (size_t)n * ld_f32 + co_f32 + cofs + lane * 2) = acc;
    }
}

// ---------------- pooling / fused MLP head ----------------

__global__ void k_pool(const float* __restrict__ h, const int* __restrict__ gid,
                       float* __restrict__ hg, float* __restrict__ gcnt) {
    const int c = threadIdx.x;  // 128
    int n0 = blockIdx.x * 64;
    if (n0 >= NN) return;
    int end = n0 + 64; if (end > NN) end = NN;
    int cur = gid[n0];
    float run = 0.f, crun = 0.f;
    for (int n = n0; n < end; ++n) {
        int g = gid[n];
        if (g != cur) {
            atomicAdd(&hg[cur * 128 + c], run);
            if (c == 0) atomicAdd(&gcnt[cur], crun);
            run = 0.f; crun = 0.f; cur = g;
        }
        run += h[(size_t)n * 128 + c];
        crun += 1.f;
    }
    atomicAdd(&hg[cur * 128 + c], run);
    if (c == 0) atomicAdd(&gcnt[cur], crun);
}

__global__ __launch_bounds__(256)
void k_head(const float* __restrict__ hg, const float* __restrict__ gcnt,
            const float* __restrict__ Wh0, const float* __restrict__ bh0,
            const float* __restrict__ Wh1, const float* __restrict__ bh1,
            const float* __restrict__ Wh2, const float* __restrict__ bh2,
            const float* __restrict__ Wc, const float* __restrict__ bc,
            float* __restrict__ out) {
    __shared__ float x0[128], x1[128], x2[256], x3[128], sl[8];
    int g = blockIdx.x, t = threadIdx.x;
    if (t < 128) {
        float c = gcnt[g];
        x0[t] = hg[g * 128 + t] / (c > 1.f ? c : 1.f);
    }
    __syncthreads();
    if (t < 128) {
        float a = bh0[t];
        for (int k = 0; k < 128; ++k) a += x0[k] * Wh0[k * 128 + t];
        x1[t] = a > 0.f ? a : 0.f;
    }
    __syncthreads();
    {
        float a = bh1[t];
        for (int k = 0; k < 128; ++k) a += x1[k] * Wh1[k * 256 + t];
        x2[t] = a > 0.f ? a : 0.f;
    }
    __syncthreads();
    if (t < 128) {
        float a = bh2[t];
        for (int k = 0; k < 256; ++k) a += x2[k] * Wh2[k * 128 + t];
        x3[t] = a > 0.f ? a : 0.f;
    }
    __syncthreads();
    if (t < 8) {
        float a = bc[t];
        for (int k = 0; k < 128; ++k) a += x3[k] * Wc[k * 8 + t];
        sl[t] = a;
    }
    __syncthreads();
    if (t == 0) {
        float m = sl[0];
        for (int c = 1; c < 8; ++c) m = sl[c] > m ? sl[c] : m;
        float s = 0.f, e[8];
        for (int c = 0; c < 8; ++c) { e[c] = expf(sl[c] - m); s += e[c]; }
        for (int c = 0; c < 8; ++c) out[g * 8 + c] = e[c] / s;
    }
}

// ---------------- launcher ----------------

extern "C" void kernel_launch(void* const* d_in, const int* in_sizes, int n_in,
                              void* d_out, int out_size, void* d_ws, size_t ws_size,
                              hipStream_t stream) {
    const float* h0   = (const float*)d_in[0];
    const int* src    = (const int*)d_in[1];
    const int* dst    = (const int*)d_in[2];
    const int* rel    = (const int*)d_in[3];
    const int* gid    = (const int*)d_in[4];
    const float* Wr0  = (const float*)d_in[5];
    const float* Wl0  = (const float*)d_in[6];
    const float* b0   = (const float*)d_in[7];
    const float* Wr1  = (const float*)d_in[8];
    const float* Wl1  = (const float*)d_in[9];
    const float* b1   = (const float*)d_in[10];
    const float* Wr2  = (const float*)d_in[11];
    const float* Wl2  = (const float*)d_in[12];
    const float* b2   = (const float*)d_in[13];
    const float* Wh0  = (const float*)d_in[14];
    const float* bh0  = (const float*)d_in[15];
    const float* Wh1  = (const float*)d_in[16];
    const float* bh1  = (const float*)d_in[17];
    const float* Wh2  = (const float*)d_in[18];
    const float* bh2  = (const float*)d_in[19];
    const float* Wc   = (const float*)d_in[20];
    const float* bc   = (const float*)d_in[21];
    float* out = (float*)d_out;

    // workspace layout (256B-aligned blocks); zero-init arrays contiguous
    char* p = (char*)d_ws;
    auto alloc = [&](size_t bytes) { char* q = p; p += (bytes + 255) & ~(size_t)255; return q; };
    float* bufS  = (float*)alloc((size_t)NN * 256 * 4);
    unsigned short* hbA = (unsigned short*)alloc((size_t)NN * 256 * 2);
    unsigned short* hbB = (unsigned short*)alloc((size_t)NN * 128 * 2);
    unsigned short* Wt0 = (unsigned short*)alloc((size_t)NR * 128 * 128 * 2);
    unsigned short* Wt1 = (unsigned short*)alloc((size_t)NR * 256 * 128 * 2);
    unsigned short* Wt2 = (unsigned short*)alloc((size_t)NR * 128 * 256 * 2);
    unsigned short* Wlt0 = (unsigned short*)alloc((size_t)128 * 128 * 2);
    unsigned short* Wlt1 = (unsigned short*)alloc((size_t)256 * 128 * 2);
    unsigned short* Wlt2 = (unsigned short*)alloc((size_t)128 * 256 * 2);
    int* srcs    = (int*)alloc((size_t)NE * 4);
    int* dstv    = (int*)alloc((size_t)NE * 4);
    int* dpos    = (int*)alloc((size_t)NE * 4);
    int* rowptr  = (int*)alloc((size_t)(NN + 1) * 4);
    int* bsum    = (int*)alloc(NB_SCAN * 4);
    int* bpref   = (int*)alloc(NB_SCAN * 4);
    int* boff    = (int*)alloc((MAXB + 1) * 4);
    int* tstart  = (int*)alloc((MAXB + 1) * 4);
    int4* tilemap = (int4*)alloc((size_t)(NE / TS + MAXB + 64) * 16);
    // ---- zero-init region (one memset) ----
    char* zbase  = p;
    int* bcnt    = (int*)alloc(MAXB * 4);
    int* cursor  = (int*)alloc(MAXB * 4);
    int* ncur    = (int*)alloc((size_t)NN * 4);
    float* hg    = (float*)alloc((size_t)NG * 128 * 4);
    float* gcnt  = (float*)alloc(NG * 4);
    size_t zlen  = (size_t)(p - zbase);
    unsigned short* msg = (unsigned short*)p;

    long long avail = (long long)ws_size - (long long)(p - (char*)d_ws);
    if (avail < (1 << 20)) avail = (1 << 20);
    long long capR64 = avail / 256;                 // bf16 rows of 128
    int C = 64;
    for (int c = 1; c <= 64; ++c) {
        double need = (double)NE / c * 1.15 + 4096.0;
        if ((double)capR64 >= need) { C = c; break; }
    }
    int npc = (NN + C - 1) / C;
    int S = MAXB / (C * NR); if (S < 1) S = 1;
    int SB = S * NR;
    int B = C * SB;
    int nps = (NN + S - 1) / S;
    int capRows = capR64 > 2000000000LL ? 2000000000 : (int)capR64;
    int TPC = (int)((double)NE / C * 1.15 / TS) + SB + 16;
    int RDB = (npc + 3) / 4;
    // fused layer-1 (256-wide msg) if capacity allows
    int fused = (C == 1 && (double)avail >= (double)NE * 1.15 * 512.0 + 2097152.0) ? 1 : 0;
    int capRows256 = (int)(avail / 512);

    // preprocessing (atomic-light): hist(buckets) -> scanb -> scatter(local ranks)
    // -> node scans -> dpos fixup -> tilemap
    hipMemsetAsync(zbase, 0, zlen, stream);
    k_hist<<<256, 256, 0, stream>>>(rel, dst, src, bcnt, npc, nps, SB, B);
    k_scanb<<<1, MAXB, 0, stream>>>(bcnt, B, boff, tstart);
    k_scatter<<<(NE + 4095) / 4096, 256, 0, stream>>>(rel, dst, src, boff, cursor, ncur, srcs, dstv, dpos, npc, nps, SB, B);
    k_scan1<<<NB_SCAN, SCAN_B, 0, stream>>>(ncur, bsum);
    k_scan2<<<1, 64, 0, stream>>>(bsum, bpref, rowptr);
    k_scan3<<<NB_SCAN, SCAN_B, 0, stream>>>(ncur, bpref, rowptr);
    k_fix<<<(NE + 255) / 256, 256, 0, stream>>>(dstv, rowptr, dpos);
    k_tilemap<<<1, MAXB, 0, stream>>>(boff, tstart, B, npc, SB, rowptr, tilemap);

    k_hconv<<<(NN * 128 / 4 + 255) / 256, 256, 0, stream>>>(h0, hbA, NN * 128 / 4);
    k_wconv_all<<<dim3(512, 6), 256, 0, stream>>>(Wr0, Wr1, Wr2, Wl0, Wl1, Wl2,
                                                  Wt0, Wt1, Wt2, Wlt0, Wlt1, Wlt2);

    const int RB = (NN + TS - 1) / TS;  // 391

    // ---- layer 0: 128 -> 128 (in hbA[ld128], out hbB bf16[ld128]) ----
    k_dense_mfma<128><<<dim3(RB, 1), 256, 0, stream>>>(hbA, Wlt0, b0, bufS, 128);
    for (int c = 0; c < C; ++c) {
        k_edge_mfma<128><<<TPC, 256, 0, stream>>>(hbA, Wt0, 128, 0, 128, 0, srcs, dpos, tilemap, tstart, c * SB, SB, msg, capRows);
        k_reduce<<<dim3(RDB, 1), 256, 0, stream>>>(msg, 128, bufS, 128, 0, hbB, 128, 0, (float*)nullptr, 0, 0, rowptr, c * npc, npc, capRows);
    }

    // ---- layer 1: 128 -> 256 (in hbB[ld128], out hbA bf16[ld256]) ----
    k_dense_mfma<128><<<dim3(RB, 2), 256, 0, stream>>>(hbB, Wlt1, b1, bufS, 256);
    if (fused) {
        k_edge_mfma<128><<<2 * TPC, 256, 0, stream>>>(hbB, Wt1, 256, 0, 256, 1, srcs, dpos, tilemap, tstart, 0, SB, msg, capRows256);
        k_reduce<<<dim3(RDB, 2), 256, 0, stream>>>(msg, 256, bufS, 256, 0, hbA, 256, 0, (float*)nullptr, 0, 0, rowptr, 0, npc, capRows256);
    } else {
        for (int half = 0; half < 2; ++half) {
            for (int c = 0; c < C; ++c) {
                k_edge_mfma<128><<<TPC, 256, 0, stream>>>(hbB, Wt1, 256, half * 128, 128, 0, srcs, dpos, tilemap, tstart, c * SB, SB, msg, capRows);
                k_reduce<<<dim3(RDB, 1), 256, 0, stream>>>(msg, 128, bufS, 256, half * 128, hbA, 256, half * 128, (float*)nullptr, 0, 0, rowptr, c * npc, npc, capRows);
            }
        }
    }

    // ---- layer 2: 256 -> 128 (in hbA[ld256], out bufS fp32[ld128] in place) ----
    k_dense_mfma<256><<<dim3(RB, 1), 256, 0, stream>>>(hbA, Wlt2, b2, bufS, 128);
    for (int c = 0; c < C; ++c) {
        k_edge_mfma<256><<<TPC, 256, 0, stream>>>(hbA, Wt2, 128, 0, 128, 0, srcs, dpos, tilemap, tstart, c * SB, SB, msg, capRows);
        k_reduce<<<dim3(RDB, 1), 256, 0, stream>>>(msg, 128, bufS, 128, 0, (unsigned short*)nullptr, 0, 0, bufS, 128, 0, rowptr, c * npc, npc, capRows);
    }

    // mean pooling + fused MLP head
    k_pool<<<(NN + 63) / 64, 128, 0, stream>>>(bufS, gid, hg, gcnt);
    k_head<<<NG, 256, 0, stream>>>(hg, gcnt, Wh0, bh0, Wh1, bh1, Wh2, bh2, Wc, bc, out);
}